// Round 11
// baseline (1205.555 us; speedup 1.0000x reference)
//
#include <hip/hip_runtime.h>
#include <hip/hip_bf16.h>

typedef __hip_bfloat16 bf16;
typedef __attribute__((ext_vector_type(8))) short short8;
typedef __attribute__((ext_vector_type(4))) short short4v;
typedef __attribute__((ext_vector_type(4))) float float4v;

#define MFMA16(a,b,c) __builtin_amdgcn_mfma_f32_16x16x32_bf16((a),(b),(c),0,0,0)

#define NB 32
#define NS 200
#define NT 199
#define NBT (NB*NT)   // 6368
#define HSTR 272      // hbuf row stride (shorts)

__device__ __forceinline__ float bf2f(bf16 x){ return __bfloat162float(x); }
__device__ __forceinline__ bf16 f2bf(float x){ return __float2bfloat16(x); }
__device__ __forceinline__ float rcp_(float x){ return __builtin_amdgcn_rcpf(x); }
__device__ __forceinline__ float sigmoidf_(float x){ return rcp_(1.0f+__expf(-x)); }
__device__ __forceinline__ float tanhf_(float x){ return 1.0f - 2.0f*rcp_(__expf(2.0f*x)+1.0f); }

union BU { bf16 b; unsigned short u; };
__device__ __forceinline__ unsigned short b2u(bf16 x){ BU t; t.b = x; return t.u; }
__device__ __forceinline__ float u2f(unsigned short x){ BU t; t.u = x; return bf2f(t.b); }

template<typename T>
__device__ __forceinline__ float ldf(const T* p, size_t i){
  if constexpr (sizeof(T) == 4) return p[i]; else return bf2f(p[i]);
}

__device__ __forceinline__ float wave_reduce(float v){
  #pragma unroll
  for (int o=32;o>0;o>>=1) v += __shfl_xor(v, o, 64);
  return v;
}

// ---- sync counters (in ws): [0..24] xchunk (UNIT counts: 32/chunk, last 28)
//                             [25..26] hprog
// RELAXED polls only; one acquire FENCE when the awaited condition first becomes true.
__device__ __forceinline__ int poll_xready_rlx(int* xchunk, int lane){
  int tgt = (lane < 25) ? ((lane == 24) ? 28 : 32) : 0;
  int v = 0;
  if (lane < 25)
    v = __hip_atomic_load(&xchunk[lane], __ATOMIC_RELAXED, __HIP_MEMORY_SCOPE_AGENT);
  unsigned long long full = __ballot(v >= tgt);
  unsigned long long notfull = ~full;
  int firstbad = (notfull == 0ULL) ? 64 : (__ffsll((unsigned long long)notfull) - 1);
  int rdy = firstbad * 8;
  return (rdy > NT) ? NT : rdy;
}

// ---- K0: detect input dtype (f32 vs bf16) from que_emb bit patterns ------------------
__global__ void k_detect(const unsigned short* qe, int* flag){
  int big = 0;
  for (int j = threadIdx.x; j < 128; j += 64){
    int ex = (qe[j] >> 7) & 0xFF;
    if (ex >= 128) big = 1;          // |bf16| >= 2.0
  }
  unsigned long long m = __ballot(big);
  if (threadIdx.x == 0) flag[0] = (__popcll(m) >= 2) ? 1 : 0;
}

__global__ void k_sentinel(void* out, int n, float v, const int* flag){
  int i = blockIdx.x*256 + threadIdx.x;
  if (i < n){ if (flag[0]) ((float*)out)[i] = v; else ((bf16*)out)[i] = f2bf(v); }
}

// ---- K0b: one-shot weight conversion to bf16 (f32 mode) / copy (bf16 mode) -----------
__global__ __launch_bounds__(1024) void k_cvt(
    const void* s0, const void* s1, const void* s2, const void* s3,
    const void* s4, const void* s5, const void* s6, const void* s7,
    bf16* out, const int* flag){
  size_t i = (size_t)blockIdx.x*1024 + threadIdx.x;
  const size_t sz[8] = {1048576,262144,589824,589824,65536,65536,4096,4096};
  const void* sp[8] = {s0,s1,s2,s3,s4,s5,s6,s7};
  size_t off = i; int s = 0;
  while (s < 8 && off >= sz[s]){ off -= sz[s]; s++; }
  if (s >= 8) return;
  if (flag[0]) out[i] = f2bf(((const float*)sp[s])[off]);
  else         out[i] = ((const bf16*)sp[s])[off];
}

// ---- K1: emb_qc[p,0:256]=que_emb[q[p]], emb_qc[p,256:512]=mean_m concept_emb[c[p,m]] -
template<typename T>
__device__ __forceinline__ void embed_body(const int* q, const int* c,
    const T* que_emb, const T* concept_emb, bf16* emb_qc){
  int p = blockIdx.x;
  int e = threadIdx.x;
  int qi = q[p];
  emb_qc[(size_t)p*512 + e] = f2bf(ldf(que_emb, (size_t)qi*256 + e));
  float s = 0.f; int cnt = 0;
  #pragma unroll
  for (int m=0;m<4;m++){
    int ci = c[p*4+m];
    if (ci >= 0){ cnt++; s += ldf(concept_emb, (size_t)ci*256 + e); }
  }
  s /= (float)(cnt > 0 ? cnt : 1);
  emb_qc[(size_t)p*512 + 256 + e] = f2bf(s);
}
__global__ __launch_bounds__(256) void k_embed(const int* q, const int* c,
    const void* qe, const void* ce, bf16* emb_qc, const int* flag, int* cnt){
  if (blockIdx.x == 0 && threadIdx.x < 32) cnt[threadIdx.x] = 0;   // zero sync counters
  if (flag[0]) embed_body<float>(q, c, (const float*)qe, (const float*)ce, emb_qc);
  else         embed_body<bf16 >(q, c, (const bf16*)qe,  (const bf16*)ce,  emb_qc);
}

// ---- gemm_x unit: Xp[t][blk][n][bi] = bf16( emb_qca @ w_ih^T + b_ih + b_hh ) ---------
// one 256-thread half computes one ny (256 N-cols) of one t. xs = 256*40 shorts local.
__device__ void gemm_x_unit(int t, int ny, int ltid, unsigned short* xs,
    const bf16* E, const int* r, const bf16* W, const bf16* bc1, const bf16* bc2, bf16* Xp){
  int lane = ltid & 63, wv = ltid >> 6;
  int col = lane & 15, quad = lane >> 4, kq = quad*8;
  const bf16* e0 = E + (size_t)(col*NS + t)*512;           // b = col
  const bf16* e1 = E + (size_t)((col+16)*NS + t)*512;      // b = col+16
  int rv0 = r[col*NS + t], rv1 = r[(col+16)*NS + t];
  int n_base = ny*256 + wv*64;
  const bf16* w0 = W + (size_t)(n_base + col)*1024 + kq;
  short8 z8 = {};
  float4v acc[2][4] = {};
  for (int k0 = 0; k0 < 1024; k0 += 32){
    bool lo = (k0 < 512);
    short8 a0 = *(const short8*)(e0 + (k0 & 511) + kq);
    short8 a1 = *(const short8*)(e1 + (k0 & 511) + kq);
    a0 = (lo == (rv0 == 0)) ? a0 : z8;
    a1 = (lo == (rv1 == 0)) ? a1 : z8;
    short8 bb[4];
    #pragma unroll
    for (int ni=0;ni<4;ni++) bb[ni] = *(const short8*)(w0 + (size_t)ni*16*1024 + k0);
    #pragma unroll
    for (int ni=0;ni<4;ni++){
      acc[0][ni] = MFMA16(a0, bb[ni], acc[0][ni]);
      acc[1][ni] = MFMA16(a1, bb[ni], acc[1][ni]);
    }
  }
  #pragma unroll
  for (int ni=0;ni<4;ni++){
    int n = n_base + ni*16 + col;
    float bs = bf2f(bc1[n]) + bf2f(bc2[n]);
    int nloc = wv*64 + ni*16 + col;
    #pragma unroll
    for (int mi=0;mi<2;mi++)
      #pragma unroll
      for (int reg=0;reg<4;reg++)
        xs[nloc*40 + mi*16 + quad*4 + reg] = b2u(f2bf(acc[mi][ni][reg] + bs));
  }
  __syncthreads();   // block-wide: both halves call this unit in lockstep
  int nloc = ltid;
  size_t n = (size_t)ny*256 + nloc;
  short8 v0 = *(const short8*)&xs[nloc*40 + 0];
  short8 v1 = *(const short8*)&xs[nloc*40 + 8];
  short8 v2 = *(const short8*)&xs[nloc*40 + 16];
  short8 v3 = *(const short8*)&xs[nloc*40 + 24];
  bf16* base = Xp + (size_t)t*2*16384 + n*16;
  *(short8*)(base)             = v0;   // blk 0, bi 0..7
  *(short8*)(base + 8)         = v1;   // blk 0, bi 8..15
  *(short8*)(base + 16384)     = v2;   // blk 1, bi 0..7
  *(short8*)(base + 16384 + 8) = v3;   // blk 1, bi 8..15
}

// ---- LSTM producer role (blocks 0,1). Zero weight VMEM in the steady state (gates
// i,f,o in registers, g in LDS). NEW vs round 10: Hg copy uses relaxed agent-scope
// sc1 WRITE-THROUGH dword stores (no dirty L2 lines), so the hprog publish is a plain
// relaxed store — the RELEASE/wbl2 that sat on the barrier path every 2 steps (the
// only structural diff vs the 557us standalone kernel) is GONE. sc1 store ACKs hide
// under the next step's ~6k-cycle body before its barrier's vmcnt drain.
__device__ void lstm_role(const bf16* Xp, const bf16* Whh, bf16* Hg,
                          unsigned short* smem, int* cnt){
  int* xchunk = cnt;
  int* hprog  = cnt + 25;
  unsigned short* wlds = smem;               // 16 tiles*8*64*8 = 65536 shorts (128 KB)
  unsigned short* hbuf = smem + 65536;       // 2*16*HSTR = 8704 shorts (17 KB)

  int lane = threadIdx.x & 63, w = threadIdx.x >> 6;   // w 0..7
  int col = lane & 15, quad = lane >> 4, kq = quad*8;
  int b0 = blockIdx.x*16;

  for (int i = threadIdx.x; i < 16*HSTR; i += 512) hbuf[i] = 0;

  // register tiles: gates 0,1 (i,f) x ct{0,1}
  short8 bfrag[4][8];
  #pragma unroll
  for (int tix=0; tix<4; tix++){
    int g = tix >> 1, ct = tix & 1;
    int nb = g*256 + w*32 + ct*16;
    #pragma unroll
    for (int ks=0; ks<8; ks++)
      bfrag[tix][ks] = *(const volatile short8*)(Whh + (size_t)(nb + col)*256 + ks*32 + kq);
  }
  // register tiles: gate 3 (o) x ct{0,1}
  short8 wofrag[2][8];
  #pragma unroll
  for (int j=0; j<2; j++){
    int nb = 3*256 + w*32 + j*16;
    #pragma unroll
    for (int ks=0; ks<8; ks++)
      wofrag[j][ks] = *(const volatile short8*)(Whh + (size_t)(nb + col)*256 + ks*32 + kq);
  }
  // LDS tiles: gate 2 (g) x ct{0,1}, lane-ordered conflict-free fragments
  #pragma unroll
  for (int j=0; j<2; j++){
    int nb = 2*256 + w*32 + j*16;
    #pragma unroll
    for (int ks=0; ks<8; ks++){
      short8 v = *(const short8*)(Whh + (size_t)(nb + col)*256 + ks*32 + kq);
      *(short8*)&wlds[(((w*2+j)*8 + ks)*64 + lane)*8] = v;
    }
  }
  __syncthreads();

  float cs[2][4] = {};
  short4v xq[8], xqn[8];

  int ready = 0;
  while (ready < 1){
    int p = poll_xready_rlx(xchunk, lane);
    if (p > ready){
      __builtin_amdgcn_fence(__ATOMIC_ACQUIRE, "agent");
      ready = p;
    } else __builtin_amdgcn_s_sleep(16);
  }
  {
    const bf16* xb = Xp + (size_t)blockIdx.x*16384 + quad*4;
    #pragma unroll
    for (int g=0; g<4; g++)
      #pragma unroll
      for (int ct=0; ct<2; ct++)
        xq[g*2+ct] = *(const short4v*)(xb + (size_t)(g*256 + w*32 + ct*16 + col)*16);
  }

  for (int t=0; t<NT; t++){
    // gate + issue next step's Xp loads early (full-step retire window)
    int tn = (t+1 < NT) ? t+1 : t;
    while (ready < tn+1){                               // no-op once all chunks seen
      int p = poll_xready_rlx(xchunk, lane);
      if (p > ready){
        __builtin_amdgcn_fence(__ATOMIC_ACQUIRE, "agent");
        ready = p;
      } else __builtin_amdgcn_s_sleep(16);
    }
    const bf16* xbn = Xp + ((size_t)tn*2 + blockIdx.x)*16384 + quad*4;
    #pragma unroll
    for (int g=0; g<4; g++)
      #pragma unroll
      for (int ct=0; ct<2; ct++)
        xqn[g*2+ct] = *(const short4v*)(xbn + (size_t)(g*256 + w*32 + ct*16 + col)*16);

    float4v acc[8];
    #pragma unroll
    for (int j=0; j<8; j++)
      #pragma unroll
      for (int rg=0; rg<4; rg++)
        acc[j][rg] = u2f((unsigned short)xq[j][rg]);    // seed with x-part

    const unsigned short* hrow = &hbuf[(t&1)*(16*HSTR) + col*HSTR + kq];
    #pragma unroll
    for (int ks=0; ks<8; ks++){
      short8 af = *(const short8*)(hrow + ks*32);
      #pragma unroll
      for (int tix=0; tix<4; tix++) acc[tix] = MFMA16(af, bfrag[tix][ks], acc[tix]);
      #pragma unroll
      for (int j=0; j<2; j++){
        short8 lw = *(const short8*)&wlds[(((w*2+j)*8 + ks)*64 + lane)*8];
        acc[4+j] = MFMA16(af, lw, acc[4+j]);
      }
      acc[6] = MFMA16(af, wofrag[0][ks], acc[6]);
      acc[7] = MFMA16(af, wofrag[1][ks], acc[7]);
    }

    unsigned short* hw = &hbuf[((t+1)&1)*(16*HSTR)];
    #pragma unroll
    for (int ct=0; ct<2; ct++){
      int hc = w*32 + ct*16 + col;
      #pragma unroll
      for (int reg=0; reg<4; reg++){
        float iv = sigmoidf_(acc[0+ct][reg]);
        float fv = sigmoidf_(acc[2+ct][reg]);
        float gv = tanhf_   (acc[4+ct][reg]);
        float ov = sigmoidf_(acc[6+ct][reg]);
        float cc = fv*cs[ct][reg] + iv*gv;
        cs[ct][reg] = cc;
        hw[(quad*4+reg)*HSTR + hc] = b2u(f2bf(ov*tanhf_(cc)));
      }
    }
    #pragma unroll
    for (int i=0;i<8;i++) xq[i] = xqn[i];
    __syncthreads();
    // barrier's vmcnt(0) ACKed step t-1's sc1 Hg stores at the coherence point ->
    // plain relaxed publish (hprog = t claims Hg[0..t-1] visible). No wbl2.
    if (threadIdx.x == 0)
      __hip_atomic_store(&hprog[blockIdx.x], t, __ATOMIC_RELAXED, __HIP_MEMORY_SCOPE_AGENT);
    // copy hbuf[(t+1)&1] -> Hg[t]: relaxed agent sc1 dword stores (write-through,
    // no dirty L2 lines). 2048 dwords over 512 threads.
    {
      const unsigned short* hb = &hbuf[((t+1)&1)*(16*HSTR)];
      unsigned int* dst = (unsigned int*)(Hg + ((size_t)t*NB + b0)*256);
      #pragma unroll
      for (int j = threadIdx.x; j < 2048; j += 512){
        int row = j >> 7, dcol = j & 127;              // 128 dwords per 256-short row
        unsigned int v = *(const unsigned int*)&hb[row*HSTR + dcol*2];
        __hip_atomic_store(dst + row*128 + dcol, v,
                           __ATOMIC_RELAXED, __HIP_MEMORY_SCOPE_AGENT);
      }
    }
  }
  __syncthreads();   // drains Hg[NT-1] sc1 stores
  if (threadIdx.x == 0)
    __hip_atomic_store(&hprog[blockIdx.x], NT, __ATOMIC_RELAXED, __HIP_MEMORY_SCOPE_AGENT);
}

// ---- head pair: one t0 per task; threads 0-255 do qn+cn (K=768), 256-511 do qa+ca
// (K=256). Rows = all 32 b at fixed t0 (coalesced Hg reads, single gate value).
#define HPAD 776
#define SPAD 264
template<typename T>
__device__ void head_pair(int t0, int tid, unsigned short* hsb, unsigned short* hss,
    const bf16* E, const bf16* Hg,
    const bf16* qn_w, const bf16* cn_w, const bf16* qa_w, const bf16* ca_w,
    const T* qn_lb, const T* qn_ow, const T* qn_ob,
    const T* cn_lb, const T* cn_ow, const T* cn_ob,
    const T* qa_lb, const T* qa_ow, const T* qa_ob,
    const T* ca_lb, const T* ca_ow, const T* ca_ob,
    const int* qshft, const int* cshft, void* out, int isf32){
  int hf = tid >> 8, ltid = tid & 255;
  int lane = ltid & 63, wv = ltid >> 6;
  int col = lane & 15, quad = lane >> 4, kq = quad*8;
  const bf16* h0 = Hg + ((size_t)t0*NB + col)*256;         // b = col
  const bf16* h1 = Hg + ((size_t)t0*NB + col + 16)*256;    // b = col+16
  const bf16* e0 = E + ((size_t)col*NS + t0 + 1)*512;
  const bf16* e1 = E + ((size_t)(col+16)*NS + t0 + 1)*512;

  for (int hd=0; hd<2; hd++){
    if (hf == 0){
      const bf16* W = hd ? cn_w : qn_w;
      const T*   Bb = hd ? cn_lb : qn_lb;
      const bf16* wb = W + (size_t)(wv*192 + col)*768 + kq;
      float4v acc[2][12] = {};
      for (int k0 = 0; k0 < 768; k0 += 32){
        short8 a0 = (k0 < 512) ? *(const short8*)(e0 + k0 + kq)
                               : *(const short8*)(h0 + (k0-512) + kq);
        short8 a1 = (k0 < 512) ? *(const short8*)(e1 + k0 + kq)
                               : *(const short8*)(h1 + (k0-512) + kq);
        #pragma unroll
        for (int ni=0; ni<12; ni++){
          short8 bv = *(const short8*)(wb + (size_t)ni*16*768 + k0);
          acc[0][ni] = MFMA16(a0, bv, acc[0][ni]);
          acc[1][ni] = MFMA16(a1, bv, acc[1][ni]);
        }
      }
      #pragma unroll
      for (int ni=0; ni<12; ni++){
        int n = wv*192 + ni*16 + col;
        float bs = ldf(Bb, n);
        #pragma unroll
        for (int mi=0; mi<2; mi++)
          #pragma unroll
          for (int reg=0; reg<4; reg++){
            int rl = mi*16 + quad*4 + reg;
            hsb[rl*HPAD + n] = b2u(f2bf(fmaxf(acc[mi][ni][reg] + bs, 0.0f)));
          }
      }
    } else {
      const bf16* W = hd ? ca_w : qa_w;
      const T*   Bb = hd ? ca_lb : qa_lb;
      const bf16* wb = W + (size_t)(wv*64 + col)*256 + kq;
      float4v acc[2][4] = {};
      for (int k0 = 0; k0 < 256; k0 += 32){
        short8 av0 = *(const short8*)(h0 + k0 + kq);
        short8 av1 = *(const short8*)(h1 + k0 + kq);
        #pragma unroll
        for (int ni=0; ni<4; ni++){
          short8 bv = *(const short8*)(wb + (size_t)ni*16*256 + k0);
          acc[0][ni] = MFMA16(av0, bv, acc[0][ni]);
          acc[1][ni] = MFMA16(av1, bv, acc[1][ni]);
        }
      }
      #pragma unroll
      for (int ni=0; ni<4; ni++){
        int n = wv*64 + ni*16 + col;
        float bs = ldf(Bb, n);
        #pragma unroll
        for (int mi=0; mi<2; mi++)
          #pragma unroll
          for (int reg=0; reg<4; reg++){
            int rl = mi*16 + quad*4 + reg;
            hss[rl*SPAD + n] = b2u(f2bf(fmaxf(acc[mi][ni][reg] + bs, 0.0f)));
          }
      }
    }
    __syncthreads();
    // gathers (rl = b, p = b*NT + t0)
    if (hf == 0){
      for (int rr=0; rr<8; rr++){
        int rl = wv*8 + rr, p = rl*NT + t0;
        if (hd == 0){
          float d = 0.f;
          for (int i=lane; i<768; i+=64) d += u2f(hsb[rl*HPAD + i]) * ldf(qn_ow, i);
          d = wave_reduce(d);
          if (lane == 0){
            float v = sigmoidf_(d + ldf(qn_ob, 0));
            if (isf32) ((float*)out)[p] = v; else ((bf16*)out)[p] = f2bf(v);
          }
        } else {
          float sum = 0.f; int cnt = 0;
          #pragma unroll
          for (int m=0; m<4; m++){
            int cid = cshft[p*4+m];
            if (cid >= 0){
              cnt++;
              const T* ww = cn_ow + (size_t)cid*768;
              float d = 0.f;
              for (int i=lane; i<768; i+=64) d += u2f(hsb[rl*HPAD + i]) * ldf(ww, i);
              d = wave_reduce(d);
              sum += sigmoidf_(d + ldf(cn_ob, cid));
            }
          }
          if (lane == 0){
            float v = sum / (float)(cnt > 0 ? cnt : 1);
            if (isf32) ((float*)out)[NBT+p] = v; else ((bf16*)out)[NBT+p] = f2bf(v);
          }
        }
      }
    } else {
      for (int rr=0; rr<8; rr++){
        int rl = wv*8 + rr, p = rl*NT + t0;
        if (hd == 0){
          int qid = qshft[p];
          const T* ww = qa_ow + (size_t)qid*256;
          float d = 0.f;
          for (int i=lane; i<256; i+=64) d += u2f(hss[rl*SPAD + i]) * ldf(ww, i);
          d = wave_reduce(d);
          if (lane == 0){
            float v = sigmoidf_(d + ldf(qa_ob, qid));
            if (isf32) ((float*)out)[2*NBT+p] = v; else ((bf16*)out)[2*NBT+p] = f2bf(v);
          }
        } else {
          float sum = 0.f; int cnt = 0;
          #pragma unroll
          for (int m=0; m<4; m++){
            int cid = cshft[p*4+m];
            if (cid >= 0){
              cnt++;
              const T* ww = ca_ow + (size_t)cid*256;
              float d = 0.f;
              for (int i=lane; i<256; i+=64) d += u2f(hss[rl*SPAD + i]) * ldf(ww, i);
              d = wave_reduce(d);
              sum += sigmoidf_(d + ldf(ca_ob, cid));
            }
          }
          if (lane == 0){
            float v = sum / (float)(cnt > 0 ? cnt : 1);
            if (isf32) ((float*)out)[3*NBT+p] = v; else ((bf16*)out)[3*NBT+p] = f2bf(v);
          }
        }
      }
    }
    __syncthreads();
  }
}

// ---- fused producer/consumer kernel. grid=201, 512 thr, 148 KB dyn LDS (=> 1 blk/CU,
// all co-resident => spins deadlock-free; dep graph gemm->lstm->heads acyclic).
// blocks 0,1: LSTM (zero weight VMEM, no wbl2 in scan). blocks 2+rank: gemm pass 0
// (units 0..397 = t 0..99 -> LSTM starts after ONE pass), gemm pass 1 (t 99..198),
// then head(t0 = rank).
__global__ __launch_bounds__(512)
__attribute__((amdgpu_waves_per_eu(2, 2)))
void k_fused(const bf16* E, const int* r, const bf16* wih, const bf16* bih, const bf16* bhh,
             bf16* Xp, const bf16* whh, bf16* Hg,
             const bf16* qn_w, const bf16* cn_w, const bf16* qa_w, const bf16* ca_w,
             const void* qn_lb, const void* qn_ow, const void* qn_ob,
             const void* cn_lb, const void* cn_ow, const void* cn_ob,
             const void* qa_lb, const void* qa_ow, const void* qa_ob,
             const void* ca_lb, const void* ca_ow, const void* ca_ob,
             const int* qshft, const int* cshft, void* out, const int* flag, int* cnt){
  extern __shared__ __align__(16) unsigned short smem[];
  int* xchunk = cnt;        // [25]
  int* hprog  = cnt + 25;   // [2]

  if (blockIdx.x < 2){
    lstm_role(Xp, whh, Hg, smem, cnt);
    return;
  }

  int rank = blockIdx.x - 2;           // 0..198
  int tid = threadIdx.x, hf = tid >> 8, ltid = tid & 255;
  volatile int* lflag = (volatile int*)(smem + 73728);  // LDS ready-flag

  // phase 1: gemm_x, 2 passes. Unit u = pass*398 + 2*rank + hf -> (t = u>>2, ny = u&3);
  // both halves of a pass share the same t. xchunk counts completed UNITS (+2/pass).
  {
    unsigned short* xs = smem + hf*(256*40);
    #pragma unroll
    for (int p = 0; p < 2; p++){
      int ub = p*398 + 2*rank;        // even
      int t  = ub >> 2;
      gemm_x_unit(t, (ub & 3) + hf, ltid, xs, E, r, wih, bih, bhh, Xp);
      __syncthreads();                // xs reuse + drain this pass's Xp stores
      if (tid == 0)
        __hip_atomic_fetch_add(&xchunk[t >> 3], 2, __ATOMIC_RELEASE, __HIP_MEMORY_SCOPE_AGENT);
        // ^ release RMW: wbl2 (consumer XCD) makes cached Xp stores visible.
    }
    if (tid == 0) *lflag = 0;
    __syncthreads();
  }

  // phase 2: wait for Hg[0..t0] (tid 0 polls relaxed + one acquire fence; rest sleep)
  int t0 = rank;
  {
    int need = t0 + 1;
    for (;;){
      if (tid == 0){
        int a = __hip_atomic_load(&hprog[0], __ATOMIC_RELAXED, __HIP_MEMORY_SCOPE_AGENT);
        int b = __hip_atomic_load(&hprog[1], __ATOMIC_RELAXED, __HIP_MEMORY_SCOPE_AGENT);
        if (a >= need && b >= need){
          __builtin_amdgcn_fence(__ATOMIC_ACQUIRE, "agent");   // one L2 inv per block
          *lflag = 1;
        }
      }
      if (*lflag) break;
      __builtin_amdgcn_s_sleep(32);
    }
  }
  __syncthreads();

  unsigned short* hsb = smem;                 // 32*776 shorts = 49,664 B
  unsigned short* hss = smem + 32*HPAD;       // 32*264 shorts = 16,896 B
  if (flag[0])
    head_pair<float>(t0, tid, hsb, hss, E, Hg, qn_w, cn_w, qa_w, ca_w,
      (const float*)qn_lb, (const float*)qn_ow, (const float*)qn_ob,
      (const float*)cn_lb, (const float*)cn_ow, (const float*)cn_ob,
      (const float*)qa_lb, (const float*)qa_ow, (const float*)qa_ob,
      (const float*)ca_lb, (const float*)ca_ow, (const float*)ca_ob,
      qshft, cshft, out, 1);
  else
    head_pair<bf16>(t0, tid, hsb, hss, E, Hg, qn_w, cn_w, qa_w, ca_w,
      (const bf16*)qn_lb, (const bf16*)qn_ow, (const bf16*)qn_ob,
      (const bf16*)cn_lb, (const bf16*)cn_ow, (const bf16*)cn_ob,
      (const bf16*)qa_lb, (const bf16*)qa_ow, (const bf16*)qa_ob,
      (const bf16*)ca_lb, (const bf16*)ca_ow, (const bf16*)ca_ob,
      qshft, cshft, out, 0);
}

// --------------------------------- host launch ----------------------------------------
extern "C" void kernel_launch(void* const* d_in, const int* in_sizes, int n_in,
                              void* d_out, int out_size, void* d_ws, size_t ws_size,
                              hipStream_t stream){
  const int*  q     = (const int*) d_in[0];
  const int*  c     = (const int*) d_in[1];
  const int*  r     = (const int*) d_in[2];
  const int*  qshft = (const int*) d_in[3];
  const int*  cshft = (const int*) d_in[4];
  const void* que_emb  = d_in[5];
  const void* conc_emb = d_in[6];
  const void* w_ih  = d_in[7];
  const void* w_hh  = d_in[8];
  const void* b_ih  = d_in[9];
  const void* b_hh  = d_in[10];
  const void* qn_lw = d_in[11];
  const void* qn_lb = d_in[12];
  const void* qn_ow = d_in[13];
  const void* qn_ob = d_in[14];
  const void* cn_lw = d_in[15];
  const void* cn_lb = d_in[16];
  const void* cn_ow = d_in[17];
  const void* cn_ob = d_in[18];
  const void* qa_lw = d_in[19];
  const void* qa_lb = d_in[20];
  const void* qa_ow = d_in[21];
  const void* qa_ob = d_in[22];
  const void* ca_lw = d_in[23];
  const void* ca_lb = d_in[24];
  const void* ca_ow = d_in[25];
  const void* ca_ob = d_in[26];

  const size_t OFF_FLAG = 0;                          // 256 B (flag @0, sync cnt @64)
  const size_t OFF_EMB  = 256;                        // 6,553,600
  const size_t OFF_XPT  = OFF_EMB + 6553600;          // 13,041,664  [t][blk][n][bi] bf16
  const size_t OFF_HG   = OFF_XPT + 13041664;         // 3,260,416   [t][b][hc] bf16
  const size_t OFF_WC   = OFF_HG + 3260416;           // 5,259,264
  const size_t NEED     = OFF_WC + 5259264;           // 28,115,200

  char* ws = (char*)d_ws;
  int* flag = (int*)(ws + OFF_FLAG);
  int* cnt  = (int*)(ws + 64);                        // 32 ints, inside flag slot

  k_detect<<<1, 64, 0, stream>>>((const unsigned short*)que_emb, flag);

  if (ws_size < NEED){
    k_sentinel<<<(out_size + 255)/256, 256, 0, stream>>>(d_out, out_size,
        (float)(ws_size >> 20), flag);
    return;
  }

  bf16* emb_qc = (bf16*)(ws + OFF_EMB);
  bf16* Xp     = (bf16*)(ws + OFF_XPT);
  bf16* Hg     = (bf16*)(ws + OFF_HG);
  bf16* Wc     = (bf16*)(ws + OFF_WC);
  bf16* wih_c  = Wc;
  bf16* whh_c  = Wc + 1048576;
  bf16* qnlw_c = Wc + 1310720;
  bf16* cnlw_c = Wc + 1900544;
  bf16* qalw_c = Wc + 2490368;
  bf16* calw_c = Wc + 2555904;
  bf16* bih_c  = Wc + 2621440;
  bf16* bhh_c  = Wc + 2625536;

  // allow 148,480 B of dynamic LDS for k_fused (CDNA4: 160 KiB/CU => 1 block/CU)
  hipFuncSetAttribute((const void*)k_fused,
      hipFuncAttributeMaxDynamicSharedMemorySize, 148480);

  k_cvt<<<2568, 1024, 0, stream>>>(w_ih, w_hh, qn_lw, cn_lw, qa_lw, ca_lw,
      b_ih, b_hh, Wc, flag);
  k_embed<<<NB*NS, 256, 0, stream>>>(q, c, que_emb, conc_emb, emb_qc, flag, cnt);
  k_fused<<<201, 512, 148480, stream>>>(emb_qc, r, wih_c, bih_c, bhh_c, Xp, whh_c, Hg,
      qnlw_c, cnlw_c, qalw_c, calw_c,
      qn_lb, qn_ow, qn_ob, cn_lb, cn_ow, cn_ob,
      qa_lb, qa_ow, qa_ob, ca_lb, ca_ow, ca_ob,
      qshft, cshft, d_out, flag, cnt);
}

// Round 12
// 987.237 us; speedup vs baseline: 1.2211x; 1.2211x over previous
//
#include <hip/hip_runtime.h>
#include <hip/hip_bf16.h>

typedef __hip_bfloat16 bf16;
typedef __attribute__((ext_vector_type(8))) short short8;
typedef __attribute__((ext_vector_type(4))) short short4v;
typedef __attribute__((ext_vector_type(4))) float float4v;

#define MFMA16(a,b,c) __builtin_amdgcn_mfma_f32_16x16x32_bf16((a),(b),(c),0,0,0)

#define NB 32
#define NS 200
#define NT 199
#define NBT (NB*NT)   // 6368
#define HSTR 272      // hbuf row stride (shorts)

__device__ __forceinline__ float bf2f(bf16 x){ return __bfloat162float(x); }
__device__ __forceinline__ bf16 f2bf(float x){ return __float2bfloat16(x); }
__device__ __forceinline__ float rcp_(float x){ return __builtin_amdgcn_rcpf(x); }
__device__ __forceinline__ float sigmoidf_(float x){ return rcp_(1.0f+__expf(-x)); }
__device__ __forceinline__ float tanhf_(float x){ return 1.0f - 2.0f*rcp_(__expf(2.0f*x)+1.0f); }

union BU { bf16 b; unsigned short u; };
__device__ __forceinline__ unsigned short b2u(bf16 x){ BU t; t.b = x; return t.u; }
__device__ __forceinline__ float u2f(unsigned short x){ BU t; t.u = x; return bf2f(t.b); }

template<typename T>
__device__ __forceinline__ float ldf(const T* p, size_t i){
  if constexpr (sizeof(T) == 4) return p[i]; else return bf2f(p[i]);
}

__device__ __forceinline__ float wave_reduce(float v){
  #pragma unroll
  for (int o=32;o>0;o>>=1) v += __shfl_xor(v, o, 64);
  return v;
}

// ---- sync counters (in ws): [0..24] xchunk (1 per completed t; target 8, last 7)
//                             [25..26] hprog
// RELAXED polls only; one acquire FENCE when the awaited condition first becomes true.
__device__ __forceinline__ int poll_xready_rlx(int* xchunk, int lane){
  int tgt = (lane < 25) ? ((lane == 24) ? 7 : 8) : 0;
  int v = 0;
  if (lane < 25)
    v = __hip_atomic_load(&xchunk[lane], __ATOMIC_RELAXED, __HIP_MEMORY_SCOPE_AGENT);
  unsigned long long full = __ballot(v >= tgt);
  unsigned long long notfull = ~full;
  int firstbad = (notfull == 0ULL) ? 64 : (__ffsll((unsigned long long)notfull) - 1);
  int rdy = firstbad * 8;
  return (rdy > NT) ? NT : rdy;
}

// ---- K0: detect input dtype (f32 vs bf16) from que_emb bit patterns ------------------
__global__ void k_detect(const unsigned short* qe, int* flag){
  int big = 0;
  for (int j = threadIdx.x; j < 128; j += 64){
    int ex = (qe[j] >> 7) & 0xFF;
    if (ex >= 128) big = 1;          // |bf16| >= 2.0
  }
  unsigned long long m = __ballot(big);
  if (threadIdx.x == 0) flag[0] = (__popcll(m) >= 2) ? 1 : 0;
}

__global__ void k_sentinel(void* out, int n, float v, const int* flag){
  int i = blockIdx.x*256 + threadIdx.x;
  if (i < n){ if (flag[0]) ((float*)out)[i] = v; else ((bf16*)out)[i] = f2bf(v); }
}

// ---- K0b: one-shot weight conversion to bf16 (f32 mode) / copy (bf16 mode) -----------
__global__ __launch_bounds__(1024) void k_cvt(
    const void* s0, const void* s1, const void* s2, const void* s3,
    const void* s4, const void* s5, const void* s6, const void* s7,
    bf16* out, const int* flag){
  size_t i = (size_t)blockIdx.x*1024 + threadIdx.x;
  const size_t sz[8] = {1048576,262144,589824,589824,65536,65536,4096,4096};
  const void* sp[8] = {s0,s1,s2,s3,s4,s5,s6,s7};
  size_t off = i; int s = 0;
  while (s < 8 && off >= sz[s]){ off -= sz[s]; s++; }
  if (s >= 8) return;
  if (flag[0]) out[i] = f2bf(((const float*)sp[s])[off]);
  else         out[i] = ((const bf16*)sp[s])[off];
}

// ---- K1: emb_qc[p,0:256]=que_emb[q[p]], emb_qc[p,256:512]=mean_m concept_emb[c[p,m]] -
template<typename T>
__device__ __forceinline__ void embed_body(const int* q, const int* c,
    const T* que_emb, const T* concept_emb, bf16* emb_qc){
  int p = blockIdx.x;
  int e = threadIdx.x;
  int qi = q[p];
  emb_qc[(size_t)p*512 + e] = f2bf(ldf(que_emb, (size_t)qi*256 + e));
  float s = 0.f; int cnt = 0;
  #pragma unroll
  for (int m=0;m<4;m++){
    int ci = c[p*4+m];
    if (ci >= 0){ cnt++; s += ldf(concept_emb, (size_t)ci*256 + e); }
  }
  s /= (float)(cnt > 0 ? cnt : 1);
  emb_qc[(size_t)p*512 + 256 + e] = f2bf(s);
}
__global__ __launch_bounds__(256) void k_embed(const int* q, const int* c,
    const void* qe, const void* ce, bf16* emb_qc, const int* flag, int* cnt){
  if (blockIdx.x == 0 && threadIdx.x < 32) cnt[threadIdx.x] = 0;   // zero sync counters
  if (flag[0]) embed_body<float>(q, c, (const float*)qe, (const float*)ce, emb_qc);
  else         embed_body<bf16 >(q, c, (const bf16*)qe,  (const bf16*)ce,  emb_qc);
}

// ---- gemm_x unit: Xp[t][blk][n][bi] = bf16( emb_qca @ w_ih^T + b_ih + b_hh ) ---------
// one 256-thread half computes one ny (256 N-cols) of one t. xs = 256*40 shorts local.
__device__ void gemm_x_unit(int t, int ny, int ltid, unsigned short* xs,
    const bf16* E, const int* r, const bf16* W, const bf16* bc1, const bf16* bc2, bf16* Xp){
  int lane = ltid & 63, wv = ltid >> 6;
  int col = lane & 15, quad = lane >> 4, kq = quad*8;
  const bf16* e0 = E + (size_t)(col*NS + t)*512;           // b = col
  const bf16* e1 = E + (size_t)((col+16)*NS + t)*512;      // b = col+16
  int rv0 = r[col*NS + t], rv1 = r[(col+16)*NS + t];
  int n_base = ny*256 + wv*64;
  const bf16* w0 = W + (size_t)(n_base + col)*1024 + kq;
  short8 z8 = {};
  float4v acc[2][4] = {};
  for (int k0 = 0; k0 < 1024; k0 += 32){
    bool lo = (k0 < 512);
    short8 a0 = *(const short8*)(e0 + (k0 & 511) + kq);
    short8 a1 = *(const short8*)(e1 + (k0 & 511) + kq);
    a0 = (lo == (rv0 == 0)) ? a0 : z8;
    a1 = (lo == (rv1 == 0)) ? a1 : z8;
    short8 bb[4];
    #pragma unroll
    for (int ni=0;ni<4;ni++) bb[ni] = *(const short8*)(w0 + (size_t)ni*16*1024 + k0);
    #pragma unroll
    for (int ni=0;ni<4;ni++){
      acc[0][ni] = MFMA16(a0, bb[ni], acc[0][ni]);
      acc[1][ni] = MFMA16(a1, bb[ni], acc[1][ni]);
    }
  }
  #pragma unroll
  for (int ni=0;ni<4;ni++){
    int n = n_base + ni*16 + col;
    float bs = bf2f(bc1[n]) + bf2f(bc2[n]);
    int nloc = wv*64 + ni*16 + col;
    #pragma unroll
    for (int mi=0;mi<2;mi++)
      #pragma unroll
      for (int reg=0;reg<4;reg++)
        xs[nloc*40 + mi*16 + quad*4 + reg] = b2u(f2bf(acc[mi][ni][reg] + bs));
  }
  __syncthreads();   // block-wide: both halves call this unit in lockstep
  int nloc = ltid;
  size_t n = (size_t)ny*256 + nloc;
  short8 v0 = *(const short8*)&xs[nloc*40 + 0];
  short8 v1 = *(const short8*)&xs[nloc*40 + 8];
  short8 v2 = *(const short8*)&xs[nloc*40 + 16];
  short8 v3 = *(const short8*)&xs[nloc*40 + 24];
  bf16* base = Xp + (size_t)t*2*16384 + n*16;
  *(short8*)(base)             = v0;   // blk 0, bi 0..7
  *(short8*)(base + 8)         = v1;   // blk 0, bi 8..15
  *(short8*)(base + 16384)     = v2;   // blk 1, bi 0..7
  *(short8*)(base + 16384 + 8) = v3;   // blk 1, bi 8..15
}

// ---- LSTM producer role (blocks 0,1). Zero weight VMEM in the steady state (gates
// i,f,o in registers, g in LDS). Hg copy = plain cached short8 stores (round-11's sc1
// write-through regressed: +3.4MB HBM writes + MALL ACK stalls). Publish cadence is
// the round-12 variable: RELEASE (wbl2, ~3us fixed L2 tag-walk) only at t=64,128,192
// + final — was every 2 steps (~100 wbl2s ~= the 300us fused-scan inflation).
__device__ void lstm_role(const bf16* Xp, const bf16* Whh, bf16* Hg,
                          unsigned short* smem, int* cnt){
  int* xchunk = cnt;
  int* hprog  = cnt + 25;
  unsigned short* wlds = smem;               // 16 tiles*8*64*8 = 65536 shorts (128 KB)
  unsigned short* hbuf = smem + 65536;       // 2*16*HSTR = 8704 shorts (17 KB)

  int lane = threadIdx.x & 63, w = threadIdx.x >> 6;   // w 0..7
  int col = lane & 15, quad = lane >> 4, kq = quad*8;
  int b0 = blockIdx.x*16;

  for (int i = threadIdx.x; i < 16*HSTR; i += 512) hbuf[i] = 0;

  // register tiles: gates 0,1 (i,f) x ct{0,1}
  short8 bfrag[4][8];
  #pragma unroll
  for (int tix=0; tix<4; tix++){
    int g = tix >> 1, ct = tix & 1;
    int nb = g*256 + w*32 + ct*16;
    #pragma unroll
    for (int ks=0; ks<8; ks++)
      bfrag[tix][ks] = *(const volatile short8*)(Whh + (size_t)(nb + col)*256 + ks*32 + kq);
  }
  // register tiles: gate 3 (o) x ct{0,1}
  short8 wofrag[2][8];
  #pragma unroll
  for (int j=0; j<2; j++){
    int nb = 3*256 + w*32 + j*16;
    #pragma unroll
    for (int ks=0; ks<8; ks++)
      wofrag[j][ks] = *(const volatile short8*)(Whh + (size_t)(nb + col)*256 + ks*32 + kq);
  }
  // LDS tiles: gate 2 (g) x ct{0,1}, lane-ordered conflict-free fragments
  #pragma unroll
  for (int j=0; j<2; j++){
    int nb = 2*256 + w*32 + j*16;
    #pragma unroll
    for (int ks=0; ks<8; ks++){
      short8 v = *(const short8*)(Whh + (size_t)(nb + col)*256 + ks*32 + kq);
      *(short8*)&wlds[(((w*2+j)*8 + ks)*64 + lane)*8] = v;
    }
  }
  __syncthreads();

  float cs[2][4] = {};
  short4v xq[8], xqn[8];

  int ready = 0;
  while (ready < 1){
    int p = poll_xready_rlx(xchunk, lane);
    if (p > ready){
      __builtin_amdgcn_fence(__ATOMIC_ACQUIRE, "agent");
      ready = p;
    } else __builtin_amdgcn_s_sleep(16);
  }
  {
    const bf16* xb = Xp + (size_t)blockIdx.x*16384 + quad*4;
    #pragma unroll
    for (int g=0; g<4; g++)
      #pragma unroll
      for (int ct=0; ct<2; ct++)
        xq[g*2+ct] = *(const short4v*)(xb + (size_t)(g*256 + w*32 + ct*16 + col)*16);
  }

  for (int t=0; t<NT; t++){
    // gate + issue next step's Xp loads early (full-step retire window)
    int tn = (t+1 < NT) ? t+1 : t;
    while (ready < tn+1){                               // no-op once all chunks seen
      int p = poll_xready_rlx(xchunk, lane);
      if (p > ready){
        __builtin_amdgcn_fence(__ATOMIC_ACQUIRE, "agent");
        ready = p;
      } else __builtin_amdgcn_s_sleep(16);
    }
    const bf16* xbn = Xp + ((size_t)tn*2 + blockIdx.x)*16384 + quad*4;
    #pragma unroll
    for (int g=0; g<4; g++)
      #pragma unroll
      for (int ct=0; ct<2; ct++)
        xqn[g*2+ct] = *(const short4v*)(xbn + (size_t)(g*256 + w*32 + ct*16 + col)*16);

    float4v acc[8];
    #pragma unroll
    for (int j=0; j<8; j++)
      #pragma unroll
      for (int rg=0; rg<4; rg++)
        acc[j][rg] = u2f((unsigned short)xq[j][rg]);    // seed with x-part

    const unsigned short* hrow = &hbuf[(t&1)*(16*HSTR) + col*HSTR + kq];
    #pragma unroll
    for (int ks=0; ks<8; ks++){
      short8 af = *(const short8*)(hrow + ks*32);
      #pragma unroll
      for (int tix=0; tix<4; tix++) acc[tix] = MFMA16(af, bfrag[tix][ks], acc[tix]);
      #pragma unroll
      for (int j=0; j<2; j++){
        short8 lw = *(const short8*)&wlds[(((w*2+j)*8 + ks)*64 + lane)*8];
        acc[4+j] = MFMA16(af, lw, acc[4+j]);
      }
      acc[6] = MFMA16(af, wofrag[0][ks], acc[6]);
      acc[7] = MFMA16(af, wofrag[1][ks], acc[7]);
    }

    unsigned short* hw = &hbuf[((t+1)&1)*(16*HSTR)];
    #pragma unroll
    for (int ct=0; ct<2; ct++){
      int hc = w*32 + ct*16 + col;
      #pragma unroll
      for (int reg=0; reg<4; reg++){
        float iv = sigmoidf_(acc[0+ct][reg]);
        float fv = sigmoidf_(acc[2+ct][reg]);
        float gv = tanhf_   (acc[4+ct][reg]);
        float ov = sigmoidf_(acc[6+ct][reg]);
        float cc = fv*cs[ct][reg] + iv*gv;
        cs[ct][reg] = cc;
        hw[(quad*4+reg)*HSTR + hc] = b2u(f2bf(ov*tanhf_(cc)));
      }
    }
    #pragma unroll
    for (int i=0;i<8;i++) xq[i] = xqn[i];
    __syncthreads();
    // sparse RELEASE publish: barrier drained Hg[0..t-1] stores to L2; wbl2 flushes
    // them to the coherence point, then hprog = t. Only 3 in-loop wbl2s total.
    if (t && ((t & 63) == 0) && threadIdx.x == 0)
      __hip_atomic_store(&hprog[blockIdx.x], t, __ATOMIC_RELEASE, __HIP_MEMORY_SCOPE_AGENT);
    // coalesced copy hbuf[(t+1)&1] -> Hg[t] (16 rows x 256 cols), plain cached stores
    {
      int ri = threadIdx.x >> 5, ci2 = threadIdx.x & 31;
      short8 v = *(const short8*)&hbuf[((t+1)&1)*(16*HSTR) + ri*HSTR + ci2*8];
      *(short8*)(Hg + ((size_t)t*NB + b0 + ri)*256 + ci2*8) = v;
    }
  }
  __syncthreads();   // drains Hg[NT-1] stores
  if (threadIdx.x == 0)
    __hip_atomic_store(&hprog[blockIdx.x], NT, __ATOMIC_RELEASE, __HIP_MEMORY_SCOPE_AGENT);
}

// ---- head pair: one t0 per task; threads 0-255 do qn+cn (K=768), 256-511 do qa+ca
// (K=256). Rows = all 32 b at fixed t0 (coalesced Hg reads, single gate value).
#define HPAD 776
#define SPAD 264
template<typename T>
__device__ void head_pair(int t0, int tid, unsigned short* hsb, unsigned short* hss,
    const bf16* E, const bf16* Hg,
    const bf16* qn_w, const bf16* cn_w, const bf16* qa_w, const bf16* ca_w,
    const T* qn_lb, const T* qn_ow, const T* qn_ob,
    const T* cn_lb, const T* cn_ow, const T* cn_ob,
    const T* qa_lb, const T* qa_ow, const T* qa_ob,
    const T* ca_lb, const T* ca_ow, const T* ca_ob,
    const int* qshft, const int* cshft, void* out, int isf32){
  int hf = tid >> 8, ltid = tid & 255;
  int lane = ltid & 63, wv = ltid >> 6;
  int col = lane & 15, quad = lane >> 4, kq = quad*8;
  const bf16* h0 = Hg + ((size_t)t0*NB + col)*256;         // b = col
  const bf16* h1 = Hg + ((size_t)t0*NB + col + 16)*256;    // b = col+16
  const bf16* e0 = E + ((size_t)col*NS + t0 + 1)*512;
  const bf16* e1 = E + ((size_t)(col+16)*NS + t0 + 1)*512;

  for (int hd=0; hd<2; hd++){
    if (hf == 0){
      const bf16* W = hd ? cn_w : qn_w;
      const T*   Bb = hd ? cn_lb : qn_lb;
      const bf16* wb = W + (size_t)(wv*192 + col)*768 + kq;
      float4v acc[2][12] = {};
      for (int k0 = 0; k0 < 768; k0 += 32){
        short8 a0 = (k0 < 512) ? *(const short8*)(e0 + k0 + kq)
                               : *(const short8*)(h0 + (k0-512) + kq);
        short8 a1 = (k0 < 512) ? *(const short8*)(e1 + k0 + kq)
                               : *(const short8*)(h1 + (k0-512) + kq);
        #pragma unroll
        for (int ni=0; ni<12; ni++){
          short8 bv = *(const short8*)(wb + (size_t)ni*16*768 + k0);
          acc[0][ni] = MFMA16(a0, bv, acc[0][ni]);
          acc[1][ni] = MFMA16(a1, bv, acc[1][ni]);
        }
      }
      #pragma unroll
      for (int ni=0; ni<12; ni++){
        int n = wv*192 + ni*16 + col;
        float bs = ldf(Bb, n);
        #pragma unroll
        for (int mi=0; mi<2; mi++)
          #pragma unroll
          for (int reg=0; reg<4; reg++){
            int rl = mi*16 + quad*4 + reg;
            hsb[rl*HPAD + n] = b2u(f2bf(fmaxf(acc[mi][ni][reg] + bs, 0.0f)));
          }
      }
    } else {
      const bf16* W = hd ? ca_w : qa_w;
      const T*   Bb = hd ? ca_lb : qa_lb;
      const bf16* wb = W + (size_t)(wv*64 + col)*256 + kq;
      float4v acc[2][4] = {};
      for (int k0 = 0; k0 < 256; k0 += 32){
        short8 av0 = *(const short8*)(h0 + k0 + kq);
        short8 av1 = *(const short8*)(h1 + k0 + kq);
        #pragma unroll
        for (int ni=0; ni<4; ni++){
          short8 bv = *(const short8*)(wb + (size_t)ni*16*256 + k0);
          acc[0][ni] = MFMA16(av0, bv, acc[0][ni]);
          acc[1][ni] = MFMA16(av1, bv, acc[1][ni]);
        }
      }
      #pragma unroll
      for (int ni=0; ni<4; ni++){
        int n = wv*64 + ni*16 + col;
        float bs = ldf(Bb, n);
        #pragma unroll
        for (int mi=0; mi<2; mi++)
          #pragma unroll
          for (int reg=0; reg<4; reg++){
            int rl = mi*16 + quad*4 + reg;
            hss[rl*SPAD + n] = b2u(f2bf(fmaxf(acc[mi][ni][reg] + bs, 0.0f)));
          }
      }
    }
    __syncthreads();
    // gathers (rl = b, p = b*NT + t0)
    if (hf == 0){
      for (int rr=0; rr<8; rr++){
        int rl = wv*8 + rr, p = rl*NT + t0;
        if (hd == 0){
          float d = 0.f;
          for (int i=lane; i<768; i+=64) d += u2f(hsb[rl*HPAD + i]) * ldf(qn_ow, i);
          d = wave_reduce(d);
          if (lane == 0){
            float v = sigmoidf_(d + ldf(qn_ob, 0));
            if (isf32) ((float*)out)[p] = v; else ((bf16*)out)[p] = f2bf(v);
          }
        } else {
          float sum = 0.f; int cnt = 0;
          #pragma unroll
          for (int m=0; m<4; m++){
            int cid = cshft[p*4+m];
            if (cid >= 0){
              cnt++;
              const T* ww = cn_ow + (size_t)cid*768;
              float d = 0.f;
              for (int i=lane; i<768; i+=64) d += u2f(hsb[rl*HPAD + i]) * ldf(ww, i);
              d = wave_reduce(d);
              sum += sigmoidf_(d + ldf(cn_ob, cid));
            }
          }
          if (lane == 0){
            float v = sum / (float)(cnt > 0 ? cnt : 1);
            if (isf32) ((float*)out)[NBT+p] = v; else ((bf16*)out)[NBT+p] = f2bf(v);
          }
        }
      }
    } else {
      for (int rr=0; rr<8; rr++){
        int rl = wv*8 + rr, p = rl*NT + t0;
        if (hd == 0){
          int qid = qshft[p];
          const T* ww = qa_ow + (size_t)qid*256;
          float d = 0.f;
          for (int i=lane; i<256; i+=64) d += u2f(hss[rl*SPAD + i]) * ldf(ww, i);
          d = wave_reduce(d);
          if (lane == 0){
            float v = sigmoidf_(d + ldf(qa_ob, qid));
            if (isf32) ((float*)out)[2*NBT+p] = v; else ((bf16*)out)[2*NBT+p] = f2bf(v);
          }
        } else {
          float sum = 0.f; int cnt = 0;
          #pragma unroll
          for (int m=0; m<4; m++){
            int cid = cshft[p*4+m];
            if (cid >= 0){
              cnt++;
              const T* ww = ca_ow + (size_t)cid*256;
              float d = 0.f;
              for (int i=lane; i<256; i+=64) d += u2f(hss[rl*SPAD + i]) * ldf(ww, i);
              d = wave_reduce(d);
              sum += sigmoidf_(d + ldf(ca_ob, cid));
            }
          }
          if (lane == 0){
            float v = sum / (float)(cnt > 0 ? cnt : 1);
            if (isf32) ((float*)out)[3*NBT+p] = v; else ((bf16*)out)[3*NBT+p] = f2bf(v);
          }
        }
      }
    }
    __syncthreads();
  }
}

// ---- fused producer/consumer kernel. grid=201, 512 thr, 148 KB dyn LDS (=> 1 blk/CU,
// all co-resident => spins deadlock-free; dep graph gemm->lstm->heads acyclic).
// blocks 0,1: LSTM. blocks 2+t0: gemm_x(t0) then head(t0), one task each.
__global__ __launch_bounds__(512)
__attribute__((amdgpu_waves_per_eu(2, 2)))
void k_fused(const bf16* E, const int* r, const bf16* wih, const bf16* bih, const bf16* bhh,
             bf16* Xp, const bf16* whh, bf16* Hg,
             const bf16* qn_w, const bf16* cn_w, const bf16* qa_w, const bf16* ca_w,
             const void* qn_lb, const void* qn_ow, const void* qn_ob,
             const void* cn_lb, const void* cn_ow, const void* cn_ob,
             const void* qa_lb, const void* qa_ow, const void* qa_ob,
             const void* ca_lb, const void* ca_ow, const void* ca_ob,
             const int* qshft, const int* cshft, void* out, const int* flag, int* cnt){
  extern __shared__ __align__(16) unsigned short smem[];
  int* xchunk = cnt;        // [25]
  int* hprog  = cnt + 25;   // [2]

  if (blockIdx.x < 2){
    lstm_role(Xp, whh, Hg, smem, cnt);
    return;
  }

  int t0  = blockIdx.x - 2;           // 0..198, one task per block
  int tid = threadIdx.x, hf = tid >> 8, ltid = tid & 255;
  volatile int* lflag = (volatile int*)(smem + 73728);  // LDS ready-flag

  // phase 1: gemm_x for t0 (4 ny units over two passes of the two 256-thread halves)
  {
    unsigned short* xs = smem + hf*(256*40);
    gemm_x_unit(t0, hf,     ltid, xs, E, r, wih, bih, bhh, Xp);
    __syncthreads();                    // protect xs reuse across passes
    gemm_x_unit(t0, 2 + hf, ltid, xs, E, r, wih, bih, bhh, Xp);
    if (tid == 0) *lflag = 0;
    __syncthreads();                    // drain all Xp stores + lflag init
    if (tid == 0)
      __hip_atomic_fetch_add(&xchunk[t0 >> 3], 1, __ATOMIC_RELEASE, __HIP_MEMORY_SCOPE_AGENT);
      // ^ release RMW: wbl2 (write-back) makes this block's cached Xp stores visible.
  }

  // phase 2: wait for Hg[0..t0] (tid 0 polls relaxed + one acquire fence; rest sleep)
  {
    int need = t0 + 1;
    for (;;){
      if (tid == 0){
        int a = __hip_atomic_load(&hprog[0], __ATOMIC_RELAXED, __HIP_MEMORY_SCOPE_AGENT);
        int b = __hip_atomic_load(&hprog[1], __ATOMIC_RELAXED, __HIP_MEMORY_SCOPE_AGENT);
        if (a >= need && b >= need){
          __builtin_amdgcn_fence(__ATOMIC_ACQUIRE, "agent");   // one L2 inv per block
          *lflag = 1;
        }
      }
      if (*lflag) break;
      __builtin_amdgcn_s_sleep(32);
    }
  }
  __syncthreads();

  unsigned short* hsb = smem;                 // 32*776 shorts = 49,664 B
  unsigned short* hss = smem + 32*HPAD;       // 32*264 shorts = 16,896 B
  if (flag[0])
    head_pair<float>(t0, tid, hsb, hss, E, Hg, qn_w, cn_w, qa_w, ca_w,
      (const float*)qn_lb, (const float*)qn_ow, (const float*)qn_ob,
      (const float*)cn_lb, (const float*)cn_ow, (const float*)cn_ob,
      (const float*)qa_lb, (const float*)qa_ow, (const float*)qa_ob,
      (const float*)ca_lb, (const float*)ca_ow, (const float*)ca_ob,
      qshft, cshft, out, 1);
  else
    head_pair<bf16>(t0, tid, hsb, hss, E, Hg, qn_w, cn_w, qa_w, ca_w,
      (const bf16*)qn_lb, (const bf16*)qn_ow, (const bf16*)qn_ob,
      (const bf16*)cn_lb, (const bf16*)cn_ow, (const bf16*)cn_ob,
      (const bf16*)qa_lb, (const bf16*)qa_ow, (const bf16*)qa_ob,
      (const bf16*)ca_lb, (const bf16*)ca_ow, (const bf16*)ca_ob,
      qshft, cshft, out, 0);
}

// --------------------------------- host launch ----------------------------------------
extern "C" void kernel_launch(void* const* d_in, const int* in_sizes, int n_in,
                              void* d_out, int out_size, void* d_ws, size_t ws_size,
                              hipStream_t stream){
  const int*  q     = (const int*) d_in[0];
  const int*  c     = (const int*) d_in[1];
  const int*  r     = (const int*) d_in[2];
  const int*  qshft = (const int*) d_in[3];
  const int*  cshft = (const int*) d_in[4];
  const void* que_emb  = d_in[5];
  const void* conc_emb = d_in[6];
  const void* w_ih  = d_in[7];
  const void* w_hh  = d_in[8];
  const void* b_ih  = d_in[9];
  const void* b_hh  = d_in[10];
  const void* qn_lw = d_in[11];
  const void* qn_lb = d_in[12];
  const void* qn_ow = d_in[13];
  const void* qn_ob = d_in[14];
  const void* cn_lw = d_in[15];
  const void* cn_lb = d_in[16];
  const void* cn_ow = d_in[17];
  const void* cn_ob = d_in[18];
  const void* qa_lw = d_in[19];
  const void* qa_lb = d_in[20];
  const void* qa_ow = d_in[21];
  const void* qa_ob = d_in[22];
  const void* ca_lw = d_in[23];
  const void* ca_lb = d_in[24];
  const void* ca_ow = d_in[25];
  const void* ca_ob = d_in[26];

  const size_t OFF_FLAG = 0;                          // 256 B (flag @0, sync cnt @64)
  const size_t OFF_EMB  = 256;                        // 6,553,600
  const size_t OFF_XPT  = OFF_EMB + 6553600;          // 13,041,664  [t][blk][n][bi] bf16
  const size_t OFF_HG   = OFF_XPT + 13041664;         // 3,260,416   [t][b][hc] bf16
  const size_t OFF_WC   = OFF_HG + 3260416;           // 5,259,264
  const size_t NEED     = OFF_WC + 5259264;           // 28,115,200

  char* ws = (char*)d_ws;
  int* flag = (int*)(ws + OFF_FLAG);
  int* cnt  = (int*)(ws + 64);                        // 32 ints, inside flag slot

  k_detect<<<1, 64, 0, stream>>>((const unsigned short*)que_emb, flag);

  if (ws_size < NEED){
    k_sentinel<<<(out_size + 255)/256, 256, 0, stream>>>(d_out, out_size,
        (float)(ws_size >> 20), flag);
    return;
  }

  bf16* emb_qc = (bf16*)(ws + OFF_EMB);
  bf16* Xp     = (bf16*)(ws + OFF_XPT);
  bf16* Hg     = (bf16*)(ws + OFF_HG);
  bf16* Wc     = (bf16*)(ws + OFF_WC);
  bf16* wih_c  = Wc;
  bf16* whh_c  = Wc + 1048576;
  bf16* qnlw_c = Wc + 1310720;
  bf16* cnlw_c = Wc + 1900544;
  bf16* qalw_c = Wc + 2490368;
  bf16* calw_c = Wc + 2555904;
  bf16* bih_c  = Wc + 2621440;
  bf16* bhh_c  = Wc + 2625536;

  // allow 148,480 B of dynamic LDS for k_fused (CDNA4: 160 KiB/CU => 1 block/CU)
  hipFuncSetAttribute((const void*)k_fused,
      hipFuncAttributeMaxDynamicSharedMemorySize, 148480);

  k_cvt<<<2568, 1024, 0, stream>>>(w_ih, w_hh, qn_lw, cn_lw, qa_lw, ca_lw,
      b_ih, b_hh, Wc, flag);
  k_embed<<<NB*NS, 256, 0, stream>>>(q, c, que_emb, conc_emb, emb_qc, flag, cnt);
  k_fused<<<201, 512, 148480, stream>>>(emb_qc, r, wih_c, bih_c, bhh_c, Xp, whh_c, Hg,
      qnlw_c, cnlw_c, qalw_c, calw_c,
      qn_lb, qn_ow, qn_ob, cn_lb, cn_ow, cn_ob,
      qa_lb, qa_ow, qa_ob, ca_lb, ca_ow, ca_ob,
      qshft, cshft, d_out, flag, cnt);
}